// Round 21
// baseline (40.301 us; speedup 1.0000x reference)
//
#include <hip/hip_runtime.h>

// Depthwise cross-correlation, B*C = 32768 planes: x[32][32] (*) k[8][8] -> out[25][25].
// softmax(weight) sums to 1.0 -> output == correlation; weight unused.
//
// Round-21 = round-20 MFMA Toeplitz with ZERO BARRIERS. One wave = one plane,
// end to end: each wave stages its own plane's x (lane l: row l>>1, half l&1;
// 4 coalesced float4 -> 2 b128 LDS writes) and its own padded tap rows
// (lanes 0..7, one ky each), then computes -- no __syncthreads anywhere, only
// a wave-local lgkmcnt(0). No cross-wave LDS flow exists, so 32 resident
// waves/CU free-run and their VMEM / LDS / MFMA phases overlap statistically.
// (r11/r15/r16/r17/r18 all kept block barriers and plateaued at 40-44us.)
// Math identical to r20: 8 ky x {2 rt x 2 ct} v_mfma_f32_16x16x32_bf16;
// B = zero-padded dual-parity Toeplitz windows; C/D: col=lane&15,
// row=(lane>>4)*4+reg (HW-verified layout).

#define NPLANES (128 * 256)
#define PPB 4                       // planes per block = waves per block
#define RST 20                      // x row stride (dwords), %4==0 for b128
#define XROWS 40                    // 32 data + 8 garbage-pad rows
#define XP (XROWS * RST)            // 800
#define TAPB (PPB * XP)             // 3200
#define TKY 48                      // per-ky tap row: 24 dw E + 24 dw O
#define TPP (8 * TKY)               // 384 dw per plane
#define LDS_DW (TAPB + PPB * TPP)   // 4736 dw = 18944 B -> 8 blocks/CU
#define OH 25
#define OW 25

typedef __attribute__((ext_vector_type(8))) short short8;    // 8 bf16 (4 VGPR)
typedef __attribute__((ext_vector_type(4))) float f32x4;     // MFMA acc
typedef __attribute__((ext_vector_type(4))) unsigned uint4v;

__device__ __forceinline__ unsigned cvt_pk_bf16(float a, float b) {
    unsigned r;  // lo = bf16(a), hi = bf16(b)
    asm("v_cvt_pk_bf16_f32 %0, %1, %2" : "=v"(r) : "v"(a), "v"(b));
    return r;
}

__global__ __launch_bounds__(256)
void dwxcorr_kernel(const float* __restrict__ x,
                    const float* __restrict__ kern,
                    float* __restrict__ out) {
    __shared__ unsigned ldsu[LDS_DW];
    const int tid  = threadIdx.x;
    const int wave = tid >> 6;
    const int l    = tid & 63;
    const int plane = blockIdx.x * PPB + wave;   // NPLANES % PPB == 0

    // ---- Per-wave staging: x rows of OWN plane ----
    {
        const int row  = l >> 1;
        const int half = l & 1;
        const float* g = x + (size_t)plane * 1024 + row * 32 + half * 16;
        const float4 v0 = *reinterpret_cast<const float4*>(g + 0);
        const float4 v1 = *reinterpret_cast<const float4*>(g + 4);
        const float4 v2 = *reinterpret_cast<const float4*>(g + 8);
        const float4 v3 = *reinterpret_cast<const float4*>(g + 12);
        uint4v w;
        unsigned* base = &ldsu[wave * XP + row * RST + half * 8];
        w.x = cvt_pk_bf16(v0.x, v0.y); w.y = cvt_pk_bf16(v0.z, v0.w);
        w.z = cvt_pk_bf16(v1.x, v1.y); w.w = cvt_pk_bf16(v1.z, v1.w);
        *reinterpret_cast<uint4v*>(base + 0) = w;
        w.x = cvt_pk_bf16(v2.x, v2.y); w.y = cvt_pk_bf16(v2.z, v2.w);
        w.z = cvt_pk_bf16(v3.x, v3.y); w.w = cvt_pk_bf16(v3.z, v3.w);
        *reinterpret_cast<uint4v*>(base + 4) = w;
    }
    // ---- Per-wave staging: padded dual-parity tap rows (lanes 0..7, ky = l) ----
    if (l < 8) {
        const int ky = l;
        const float* g = kern + (size_t)plane * 64 + ky * 8;
        const float4 v0 = *reinterpret_cast<const float4*>(g + 0);
        const float4 v1 = *reinterpret_cast<const float4*>(g + 4);
        const unsigned K0 = cvt_pk_bf16(v0.x, v0.y);
        const unsigned K1 = cvt_pk_bf16(v0.z, v0.w);
        const unsigned K2 = cvt_pk_bf16(v1.x, v1.y);
        const unsigned K3 = cvt_pk_bf16(v1.z, v1.w);
        const unsigned O7  = cvt_pk_bf16(0.f, v0.x);   // (tap[-1]=0, tap0)
        const unsigned O8  = cvt_pk_bf16(v0.y, v0.z);  // (tap1, tap2)
        const unsigned O9  = cvt_pk_bf16(v0.w, v1.x);  // (tap3, tap4)
        const unsigned O10 = cvt_pk_bf16(v1.y, v1.z);  // (tap5, tap6)
        const unsigned O11 = cvt_pk_bf16(v1.w, 0.f);   // (tap7, tap[8]=0)
        unsigned* tb = &ldsu[TAPB + wave * TPP + ky * TKY];
        const uint4v z = {0u, 0u, 0u, 0u};
        uint4v m;
        *reinterpret_cast<uint4v*>(tb + 0)  = z;
        *reinterpret_cast<uint4v*>(tb + 4)  = z;
        m.x = K0; m.y = K1; m.z = K2; m.w = K3;
        *reinterpret_cast<uint4v*>(tb + 8)  = m;       // E[8..11]
        *reinterpret_cast<uint4v*>(tb + 12) = z;
        *reinterpret_cast<uint4v*>(tb + 16) = z;
        *reinterpret_cast<uint4v*>(tb + 20) = z;
        *reinterpret_cast<uint4v*>(tb + 24) = z;       // O[0..3]
        m.x = 0u; m.y = 0u; m.z = 0u; m.w = O7;
        *reinterpret_cast<uint4v*>(tb + 28) = m;       // O[4..7]
        m.x = O8; m.y = O9; m.z = O10; m.w = O11;
        *reinterpret_cast<uint4v*>(tb + 32) = m;       // O[8..11]
        *reinterpret_cast<uint4v*>(tb + 36) = z;
        *reinterpret_cast<uint4v*>(tb + 40) = z;
        *reinterpret_cast<uint4v*>(tb + 44) = z;
    }

    // Wave-local fence: own writes -> own reads (LDS per-wave in-order; this
    // also stops the compiler from reordering reads above the writes).
    asm volatile("s_waitcnt lgkmcnt(0)" ::: "memory");
    __builtin_amdgcn_sched_barrier(0);

    // ---- Compute (identical to r20) ----
    const int c = l & 15;             // A row offset / B-D col
    const int a = l >> 4;             // k-block (k = 8a..8a+7)

    const unsigned* xb = &ldsu[wave * XP + 4 * a];
    const unsigned* tb = &ldsu[TAPB + wave * TPP];

    int off0, off1;
    {
        int s = 8 * a - c;                       // ct = 0
        int st = (s >> 1) + 8;
        st = st < 0 ? 0 : (st > 20 ? 20 : st);
        off0 = (s & 1) * 24 + st;
        s = 8 * a - 16 - c;                      // ct = 1
        st = (s >> 1) + 8;
        st = st < 0 ? 0 : (st > 20 ? 20 : st);
        off1 = (s & 1) * 24 + st;
    }

    f32x4 acc00 = {0.f, 0.f, 0.f, 0.f};
    f32x4 acc01 = {0.f, 0.f, 0.f, 0.f};
    f32x4 acc10 = {0.f, 0.f, 0.f, 0.f};
    f32x4 acc11 = {0.f, 0.f, 0.f, 0.f};

#pragma unroll
    for (int ky = 0; ky < 8; ++ky) {
        const short8 a0 =
            *reinterpret_cast<const short8*>(xb + (ky + c) * RST);
        const short8 a1 =
            *reinterpret_cast<const short8*>(xb + (16 + ky + c) * RST);
        const unsigned* bp = tb + ky * TKY;
        uint4v bu0, bu1;
        bu0.x = bp[off0 + 0]; bu0.y = bp[off0 + 1];
        bu0.z = bp[off0 + 2]; bu0.w = bp[off0 + 3];
        bu1.x = bp[off1 + 0]; bu1.y = bp[off1 + 1];
        bu1.z = bp[off1 + 2]; bu1.w = bp[off1 + 3];
        const short8 b0 = __builtin_bit_cast(short8, bu0);
        const short8 b1 = __builtin_bit_cast(short8, bu1);
        acc00 = __builtin_amdgcn_mfma_f32_16x16x32_bf16(a0, b0, acc00, 0, 0, 0);
        acc01 = __builtin_amdgcn_mfma_f32_16x16x32_bf16(a0, b1, acc01, 0, 0, 0);
        acc10 = __builtin_amdgcn_mfma_f32_16x16x32_bf16(a1, b0, acc10, 0, 0, 0);
        acc11 = __builtin_amdgcn_mfma_f32_16x16x32_bf16(a1, b1, acc11, 0, 0, 0);
    }

    // ---- Stores: D[row][col], row = 4a+reg (+16 rt1), col = c (+16 ct1) ----
    float* op = out + (size_t)plane * (OH * OW);
#pragma unroll
    for (int reg = 0; reg < 4; ++reg) {
        const int r0 = 4 * a + reg;              // 0..15
        op[r0 * OW + c] = acc00[reg];
        if (c <= 8) op[r0 * OW + 16 + c] = acc01[reg];
        if (r0 <= 8) {
            op[(16 + r0) * OW + c] = acc10[reg];
            if (c <= 8) op[(16 + r0) * OW + 16 + c] = acc11[reg];
        }
    }
}

extern "C" void kernel_launch(void* const* d_in, const int* in_sizes, int n_in,
                              void* d_out, int out_size, void* d_ws, size_t ws_size,
                              hipStream_t stream) {
    const float* x = (const float*)d_in[0];
    const float* k = (const float*)d_in[1];
    // d_in[2] (weight) unused: softmax weights sum to exactly 1.
    float* out = (float*)d_out;
    const int nblocks = NPLANES / PPB;   // 8192
    dwxcorr_kernel<<<nblocks, 256, 0, stream>>>(x, k, out);
}

// Round 22
// 39.964 us; speedup vs baseline: 1.0084x; 1.0084x over previous
//
#include <hip/hip_runtime.h>

// Depthwise cross-correlation, B*C = 32768 planes: x[32][32] (*) k[8][8] -> out[25][25].
// softmax(weight) sums to 1.0 -> output == correlation; weight unused.
//
// Round-22 = round-21 (barrier-free MFMA Toeplitz, one wave = one plane) with
// COMPRESSED TAP STAGING. r21 spent 12 b128 wave-instrs (8 active lanes) on
// the 96-dword padded tap rows; now: zero-fill the 384-dw region with all 64
// lanes (1 b128 + 1 b64 = 2 instrs), then write the only 3 nonzero quads per
// ky with lanes 0..23 (lane = 3*ky+q, taps from global/L1) = 1 b128 instr.
// Same-wave LDS ops are ordered, so zero-fill -> quad-write is race-free.
// Compute identical to r20/r21: 8 ky x {2rt x 2ct} v_mfma_f32_16x16x32_bf16,
// B = zero-padded dual-parity Toeplitz windows, C/D col=lane&15,
// row=(lane>>4)*4+reg.

#define NPLANES (128 * 256)
#define PPB 4                       // planes per block = waves per block
#define RST 20                      // x row stride (dwords), %4==0 for b128
#define XROWS 40                    // 32 data + 8 garbage-pad rows
#define XP (XROWS * RST)            // 800
#define TAPB (PPB * XP)             // 3200
#define TKY 48                      // per-ky tap row: 24 dw E + 24 dw O
#define TPP (8 * TKY)               // 384 dw per plane
#define LDS_DW (TAPB + PPB * TPP)   // 4736 dw = 18944 B -> 8 blocks/CU
#define OH 25
#define OW 25

typedef __attribute__((ext_vector_type(8))) short short8;    // 8 bf16 (4 VGPR)
typedef __attribute__((ext_vector_type(4))) float f32x4;     // MFMA acc
typedef __attribute__((ext_vector_type(4))) unsigned uint4v;

__device__ __forceinline__ unsigned cvt_pk_bf16(float a, float b) {
    unsigned r;  // lo = bf16(a), hi = bf16(b)
    asm("v_cvt_pk_bf16_f32 %0, %1, %2" : "=v"(r) : "v"(a), "v"(b));
    return r;
}

__global__ __launch_bounds__(256)
void dwxcorr_kernel(const float* __restrict__ x,
                    const float* __restrict__ kern,
                    float* __restrict__ out) {
    __shared__ unsigned ldsu[LDS_DW];
    const int tid  = threadIdx.x;
    const int wave = tid >> 6;
    const int l    = tid & 63;
    const int plane = blockIdx.x * PPB + wave;   // NPLANES % PPB == 0

    // ---- Per-wave staging: x rows of OWN plane (lane l: row l>>1, half l&1) ----
    {
        const int row  = l >> 1;
        const int half = l & 1;
        const float* g = x + (size_t)plane * 1024 + row * 32 + half * 16;
        const float4 v0 = *reinterpret_cast<const float4*>(g + 0);
        const float4 v1 = *reinterpret_cast<const float4*>(g + 4);
        const float4 v2 = *reinterpret_cast<const float4*>(g + 8);
        const float4 v3 = *reinterpret_cast<const float4*>(g + 12);
        uint4v w;
        unsigned* base = &ldsu[wave * XP + row * RST + half * 8];
        w.x = cvt_pk_bf16(v0.x, v0.y); w.y = cvt_pk_bf16(v0.z, v0.w);
        w.z = cvt_pk_bf16(v1.x, v1.y); w.w = cvt_pk_bf16(v1.z, v1.w);
        *reinterpret_cast<uint4v*>(base + 0) = w;
        w.x = cvt_pk_bf16(v2.x, v2.y); w.y = cvt_pk_bf16(v2.z, v2.w);
        w.z = cvt_pk_bf16(v3.x, v3.y); w.w = cvt_pk_bf16(v3.z, v3.w);
        *reinterpret_cast<uint4v*>(base + 4) = w;
    }

    // ---- Compressed tap staging ----
    const int tb0 = TAPB + wave * TPP;
    {   // zero-fill 384 dw with all 64 lanes: 1 b128 + 1 b64
        const uint4v z4 = {0u, 0u, 0u, 0u};
        *reinterpret_cast<uint4v*>(&ldsu[tb0 + 4 * l]) = z4;          // 0..255
        *reinterpret_cast<uint2*>(&ldsu[tb0 + 256 + 2 * l]) =
            make_uint2(0u, 0u);                                       // 256..383
    }
    if (l < 24) {   // 3 nonzero quads per ky; lane = 3*ky + q
        const int ky = l / 3;
        const int q  = l - 3 * ky;
        const float* g = kern + (size_t)plane * 64 + ky * 8;
        const float4 v0 = *reinterpret_cast<const float4*>(g + 0);
        const float4 v1 = *reinterpret_cast<const float4*>(g + 4);
        uint4v m;
        int off;
        if (q == 0) {            // E[8..11] = packed even pairs
            m.x = cvt_pk_bf16(v0.x, v0.y); m.y = cvt_pk_bf16(v0.z, v0.w);
            m.z = cvt_pk_bf16(v1.x, v1.y); m.w = cvt_pk_bf16(v1.z, v1.w);
            off = 8;
        } else if (q == 1) {     // O[4..7] = (0,0,0,(pad,tap0))
            m.x = 0u; m.y = 0u; m.z = 0u;
            m.w = cvt_pk_bf16(0.f, v0.x);
            off = 28;
        } else {                 // O[8..11] = odd-shifted pairs
            m.x = cvt_pk_bf16(v0.y, v0.z); m.y = cvt_pk_bf16(v0.w, v1.x);
            m.z = cvt_pk_bf16(v1.y, v1.z); m.w = cvt_pk_bf16(v1.w, 0.f);
            off = 32;
        }
        *reinterpret_cast<uint4v*>(&ldsu[tb0 + ky * TKY + off]) = m;
    }

    // Wave-local fence: own writes -> own reads (same-wave LDS ops in order;
    // also stops the compiler hoisting reads above the writes).
    asm volatile("s_waitcnt lgkmcnt(0)" ::: "memory");
    __builtin_amdgcn_sched_barrier(0);

    // ---- Compute (identical to r20/r21) ----
    const int c = l & 15;             // A row offset / B-D col
    const int a = l >> 4;             // k-block (k = 8a..8a+7)

    const unsigned* xb = &ldsu[wave * XP + 4 * a];
    const unsigned* tb = &ldsu[tb0];

    int off0, off1;
    {
        int s = 8 * a - c;                       // ct = 0
        int st = (s >> 1) + 8;
        st = st < 0 ? 0 : (st > 20 ? 20 : st);
        off0 = (s & 1) * 24 + st;
        s = 8 * a - 16 - c;                      // ct = 1
        st = (s >> 1) + 8;
        st = st < 0 ? 0 : (st > 20 ? 20 : st);
        off1 = (s & 1) * 24 + st;
    }

    f32x4 acc00 = {0.f, 0.f, 0.f, 0.f};
    f32x4 acc01 = {0.f, 0.f, 0.f, 0.f};
    f32x4 acc10 = {0.f, 0.f, 0.f, 0.f};
    f32x4 acc11 = {0.f, 0.f, 0.f, 0.f};

#pragma unroll
    for (int ky = 0; ky < 8; ++ky) {
        const short8 a0 =
            *reinterpret_cast<const short8*>(xb + (ky + c) * RST);
        const short8 a1 =
            *reinterpret_cast<const short8*>(xb + (16 + ky + c) * RST);
        const unsigned* bp = tb + ky * TKY;
        uint4v bu0, bu1;
        bu0.x = bp[off0 + 0]; bu0.y = bp[off0 + 1];
        bu0.z = bp[off0 + 2]; bu0.w = bp[off0 + 3];
        bu1.x = bp[off1 + 0]; bu1.y = bp[off1 + 1];
        bu1.z = bp[off1 + 2]; bu1.w = bp[off1 + 3];
        const short8 b0 = __builtin_bit_cast(short8, bu0);
        const short8 b1 = __builtin_bit_cast(short8, bu1);
        acc00 = __builtin_amdgcn_mfma_f32_16x16x32_bf16(a0, b0, acc00, 0, 0, 0);
        acc01 = __builtin_amdgcn_mfma_f32_16x16x32_bf16(a0, b1, acc01, 0, 0, 0);
        acc10 = __builtin_amdgcn_mfma_f32_16x16x32_bf16(a1, b0, acc10, 0, 0, 0);
        acc11 = __builtin_amdgcn_mfma_f32_16x16x32_bf16(a1, b1, acc11, 0, 0, 0);
    }

    // ---- Stores: D[row][col], row = 4a+reg (+16 rt1), col = c (+16 ct1) ----
    float* op = out + (size_t)plane * (OH * OW);
#pragma unroll
    for (int reg = 0; reg < 4; ++reg) {
        const int r0 = 4 * a + reg;              // 0..15
        op[r0 * OW + c] = acc00[reg];
        if (c <= 8) op[r0 * OW + 16 + c] = acc01[reg];
        if (r0 <= 8) {
            op[(16 + r0) * OW + c] = acc10[reg];
            if (c <= 8) op[(16 + r0) * OW + 16 + c] = acc11[reg];
        }
    }
}

extern "C" void kernel_launch(void* const* d_in, const int* in_sizes, int n_in,
                              void* d_out, int out_size, void* d_ws, size_t ws_size,
                              hipStream_t stream) {
    const float* x = (const float*)d_in[0];
    const float* k = (const float*)d_in[1];
    // d_in[2] (weight) unused: softmax weights sum to exactly 1.
    float* out = (float*)d_out;
    const int nblocks = NPLANES / PPB;   // 8192
    dwxcorr_kernel<<<nblocks, 256, 0, stream>>>(x, k, out);
}